// Round 1
// baseline (155.420 us; speedup 1.0000x reference)
//
#include <hip/hip_runtime.h>
#include <hip/hip_bf16.h>
#include <math.h>

#define Bb 8
#define Tt 512
#define Cc 512
#define Hh 8
#define HKV 4
#define Dd 64

typedef __attribute__((ext_vector_type(8))) short short8;
typedef __attribute__((ext_vector_type(4))) float float4v;
typedef __attribute__((ext_vector_type(2))) __fp16 h2;   // matches cvt_pkrtz return
typedef __attribute__((ext_vector_type(8))) __fp16 half8; // f16 MFMA fragment

__device__ __forceinline__ h2 u2h(unsigned u) {
  union { unsigned u; h2 h; } x; x.u = u; return x.h;
}
__device__ __forceinline__ unsigned h2u(h2 h) {
  union { h2 h; unsigned u; } x; x.h = h; return x.u;
}
__device__ __forceinline__ float fdot2(h2 a, h2 b, float c) {
#if __has_builtin(__builtin_amdgcn_fdot2)
  return __builtin_amdgcn_fdot2(a, b, c, false);
#else
  return fmaf((float)a.x, (float)b.x, fmaf((float)a.y, (float)b.y, c));
#endif
}

__device__ __forceinline__ float wave_reduce_sum(float v) {
#pragma unroll
  for (int off = 32; off > 0; off >>= 1) v += __shfl_xor(v, off, 64);
  return v;
}
__device__ __forceinline__ unsigned pack_bf2(float a, float b) {
  __hip_bfloat162 h = __float22bfloat162_rn(make_float2(a, b));
  return *(unsigned*)&h;
}

// ---------------- fused prep: conv_x | conv_w | build_pw (by block range) ----------------
__global__ __launch_bounds__(256) void prep(
    const float* __restrict__ x, const float* __restrict__ Wq,
    const float* __restrict__ Wk, const float* __restrict__ Wv,
    const float* __restrict__ Wp, const float* __restrict__ P,
    const float* __restrict__ sigma,
    unsigned short* __restrict__ xb, unsigned short* __restrict__ Wtq,
    unsigned short* __restrict__ Wtp, unsigned short* __restrict__ Pwh) {
  const int bid = blockIdx.x;
  const int t = threadIdx.x;
  if (bid < 1024) {
    int i = (bid * 256 + t) * 8;
    float4 f0 = *(const float4*)&x[i];
    float4 f1 = *(const float4*)&x[i + 4];
    unsigned u[4] = {pack_bf2(f0.x, f0.y), pack_bf2(f0.z, f0.w),
                     pack_bf2(f1.x, f1.y), pack_bf2(f1.z, f1.w)};
    *(uint4*)&xb[i] = *(uint4*)u;
  } else if (bid < 1216) {
    __shared__ float Ts[64][65];
    const int bx = bid - 1024;
    const int k0 = (bx & 7) << 6;
    const int n0 = (bx >> 3) << 6;
    const float* src; int ld, nc0; unsigned short* dst; int ndst;
    if (n0 < 512)       { src = Wq; ld = 512; nc0 = n0;        dst = Wtq; ndst = n0; }
    else if (n0 < 768)  { src = Wk; ld = 256; nc0 = n0 - 512;  dst = Wtq; ndst = n0; }
    else if (n0 < 1024) { src = Wv; ld = 256; nc0 = n0 - 768;  dst = Wtq; ndst = n0; }
    else                { src = Wp; ld = 512; nc0 = n0 - 1024; dst = Wtp; ndst = n0 - 1024; }
    const int r = t >> 4, c4 = (t & 15) << 2;
#pragma unroll
    for (int rr = 0; rr < 4; ++rr) {
      int row = (rr << 4) + r;
      float4 f = *(const float4*)&src[(k0 + row) * ld + nc0 + c4];
      Ts[row][c4] = f.x; Ts[row][c4 + 1] = f.y;
      Ts[row][c4 + 2] = f.z; Ts[row][c4 + 3] = f.w;
    }
    __syncthreads();
#pragma unroll
    for (int rr = 0; rr < 4; ++rr) {
      int nr = (rr << 4) + r;
      unsigned u0 = pack_bf2(Ts[c4][nr], Ts[c4 + 1][nr]);
      unsigned u1 = pack_bf2(Ts[c4 + 2][nr], Ts[c4 + 3][nr]);
      *(uint2*)&dst[(ndst + nr) * 512 + k0 + c4] = make_uint2(u0, u1);
    }
  } else {
    int idx = (bid - 1216) * 256 + t;
    int d = idx & 63;
    int rem = idx >> 6;
    int dd = rem % 1023;
    int h = rem / 1023;
    float s = fabsf(sigma[h]) + 1e-6f;
    float delta = (float)(dd - 511);
    float dt = 128.0f * tanhf(delta / s) + 128.0f;
    float lo = floorf(dt);
    int ilo = (int)lo;
    float frac = dt - lo;
    ilo = max(0, min(ilo, 256));
    int ihi = min(ilo + 1, 256);
    const float* Pb = P + h * 257 * 64;
    float val = (1.0f - frac) * Pb[ilo * 64 + d] + frac * Pb[ihi * 64 + d];
    __fp16 hv = (__fp16)val;
    Pwh[idx] = *(unsigned short*)&hv;
  }
}

// ---------------- QKV MFMA GEMM: 64x64 tile, padded LDS; v emitted TRANSPOSED ----------------
__global__ __launch_bounds__(256) void qkv_mfma(
    const unsigned short* __restrict__ xb, const unsigned short* __restrict__ Wt,
    unsigned short* __restrict__ qh, unsigned short* __restrict__ kh,
    unsigned short* __restrict__ vT) {
  __shared__ unsigned short As[64][72];
  __shared__ unsigned short Bs[64][72];
  const int m0 = blockIdx.x * 64;
  const int n0 = blockIdx.y * 64;
  const int t = threadIdx.x;
  const int w = t >> 6, lane = t & 63;
  const int srow = t >> 2, sc = (t & 3) << 4;
  float4v acc[4] = {{0,0,0,0},{0,0,0,0},{0,0,0,0},{0,0,0,0}};
  for (int k0 = 0; k0 < 512; k0 += 64) {
    uint4 a0 = *(const uint4*)&xb[(m0 + srow) * 512 + k0 + sc];
    uint4 a1 = *(const uint4*)&xb[(m0 + srow) * 512 + k0 + sc + 8];
    uint4 b0 = *(const uint4*)&Wt[(n0 + srow) * 512 + k0 + sc];
    uint4 b1 = *(const uint4*)&Wt[(n0 + srow) * 512 + k0 + sc + 8];
    __syncthreads();
    *(uint4*)&As[srow][sc] = a0; *(uint4*)&As[srow][sc + 8] = a1;
    *(uint4*)&Bs[srow][sc] = b0; *(uint4*)&Bs[srow][sc + 8] = b1;
    __syncthreads();
    const int ml = (w << 4) + (lane & 15);
    const int kq = (lane >> 4) << 3;
    short8 aF0 = *(short8*)&As[ml][kq];
    short8 aF1 = *(short8*)&As[ml][kq + 32];
#pragma unroll
    for (int nt = 0; nt < 4; ++nt) {
      const int nl = (nt << 4) + (lane & 15);
      short8 bF0 = *(short8*)&Bs[nl][kq];
      short8 bF1 = *(short8*)&Bs[nl][kq + 32];
      acc[nt] = __builtin_amdgcn_mfma_f32_16x16x32_bf16(aF0, bF0, acc[nt], 0, 0, 0);
      acc[nt] = __builtin_amdgcn_mfma_f32_16x16x32_bf16(aF1, bF1, acc[nt], 0, 0, 0);
    }
  }
  const int lane15 = lane & 15;
  const int rowbase = m0 + (w << 4) + ((lane >> 4) << 2);
  if (n0 < 768) {
    // q or k head: fused RMS-norm over the 64-wide head (= this n-tile)
#pragma unroll
    for (int r = 0; r < 4; ++r) {
      float ss = 0.0f;
#pragma unroll
      for (int nt = 0; nt < 4; ++nt) ss = fmaf(acc[nt][r], acc[nt][r], ss);
#pragma unroll
      for (int off = 1; off < 16; off <<= 1) ss += __shfl_xor(ss, off, 64);
      float sc2 = 8.0f * rsqrtf(ss + 1e-6f);
      const int row = rowbase + r;
      if (n0 < 512) {
        const int h = n0 >> 6;
#pragma unroll
        for (int nt = 0; nt < 4; ++nt) {
          __fp16 hv = (__fp16)(acc[nt][r] * sc2);
          qh[(row * Hh + h) * Dd + (nt << 4) + lane15] = *(unsigned short*)&hv;
        }
      } else {
        const int hkv = (n0 - 512) >> 6;
#pragma unroll
        for (int nt = 0; nt < 4; ++nt) {
          __fp16 hv = (__fp16)(acc[nt][r] * sc2);
          kh[(row * HKV + hkv) * Dd + (nt << 4) + lane15] = *(unsigned short*)&hv;
        }
      }
    }
  } else {
    // v transposed: vT[((b*HKV+hkv)*64 + d)*512 + t], 4 consecutive t per store
    const int hkv = (n0 - 768) >> 6;
    const int bb = rowbase >> 9;       // batch (64-row tile is within one b)
    const int trow = rowbase & 511;
#pragma unroll
    for (int nt = 0; nt < 4; ++nt) {
      const int d = (nt << 4) + lane15;
      unsigned u0 = h2u(__builtin_amdgcn_cvt_pkrtz(acc[nt][0], acc[nt][1]));
      unsigned u1 = h2u(__builtin_amdgcn_cvt_pkrtz(acc[nt][2], acc[nt][3]));
      *(uint2*)&vT[((bb * HKV + hkv) * 64 + d) * 512 + trow] = make_uint2(u0, u1);
    }
  }
}

// ---------------- Proj MFMA GEMM: 64x64 tile, padded LDS ----------------
__global__ __launch_bounds__(256) void proj_mfma(
    const unsigned short* __restrict__ yb, const unsigned short* __restrict__ Wt,
    float* __restrict__ out) {
  __shared__ unsigned short As[64][72];
  __shared__ unsigned short Bs[64][72];
  const int m0 = blockIdx.x * 64;
  const int n0 = blockIdx.y * 64;
  const int t = threadIdx.x;
  const int w = t >> 6, lane = t & 63;
  const int srow = t >> 2, sc = (t & 3) << 4;
  float4v acc[4] = {{0,0,0,0},{0,0,0,0},{0,0,0,0},{0,0,0,0}};
  for (int k0 = 0; k0 < 512; k0 += 64) {
    uint4 a0 = *(const uint4*)&yb[(m0 + srow) * 512 + k0 + sc];
    uint4 a1 = *(const uint4*)&yb[(m0 + srow) * 512 + k0 + sc + 8];
    uint4 b0 = *(const uint4*)&Wt[(n0 + srow) * 512 + k0 + sc];
    uint4 b1 = *(const uint4*)&Wt[(n0 + srow) * 512 + k0 + sc + 8];
    __syncthreads();
    *(uint4*)&As[srow][sc] = a0; *(uint4*)&As[srow][sc + 8] = a1;
    *(uint4*)&Bs[srow][sc] = b0; *(uint4*)&Bs[srow][sc + 8] = b1;
    __syncthreads();
    const int ml = (w << 4) + (lane & 15);
    const int kq = (lane >> 4) << 3;
    short8 aF0 = *(short8*)&As[ml][kq];
    short8 aF1 = *(short8*)&As[ml][kq + 32];
#pragma unroll
    for (int nt = 0; nt < 4; ++nt) {
      const int nl = (nt << 4) + (lane & 15);
      short8 bF0 = *(short8*)&Bs[nl][kq];
      short8 bF1 = *(short8*)&Bs[nl][kq + 32];
      acc[nt] = __builtin_amdgcn_mfma_f32_16x16x32_bf16(aF0, bF0, acc[nt], 0, 0, 0);
      acc[nt] = __builtin_amdgcn_mfma_f32_16x16x32_bf16(aF1, bF1, acc[nt], 0, 0, 0);
    }
  }
#pragma unroll
  for (int nt = 0; nt < 4; ++nt) {
    int col = n0 + (nt << 4) + (lane & 15);
#pragma unroll
    for (int r = 0; r < 4; ++r) {
      int row = m0 + (w << 4) + ((lane >> 4) << 2) + r;
      out[row * 512 + col] = acc[nt][r];
    }
  }
}

// ---------------- Attention v10: 8-wave blocks for occupancy ----------------
// v9 counters: VALUBusy 52%, Occupancy 33% (grid 1024 x 256thr = 4 blk/CU = 50% cap).
// v10: 512 threads (8 waves), same grid -> 32 waves/CU target. Each wave owns
// 4 score rows (was 8) and ONE 16x16 PV tile (i-half x d-quarter; was 2).
// Per-block LDS traffic / staging / MFMA totals unchanged; K reg-loads 2x (L1-hot).
__global__ __launch_bounds__(512, 8) void attn(
    const unsigned short* __restrict__ qh, const unsigned short* __restrict__ kh,
    const unsigned short* __restrict__ vT, const unsigned short* __restrict__ Pwh,
    unsigned short* __restrict__ yb) {
  __shared__ __fp16 PwS[96][72];
  __shared__ __fp16 pS[32][72];   // padded: A-frag start bank = 4*(i+joct) -> 2-way
  __shared__ float lS[32];

  const int t = threadIdx.x;
  const int lane = t & 63;
  const int wu = __builtin_amdgcn_readfirstlane(t >> 6);  // 0..7
  const int bh = blockIdx.x;
  const int b = bh >> 3;
  const int h = bh & 7;
  const int hkv = h >> 1;
  const int i0 = 480 - blockIdx.y * 32;  // heavy blocks first

  float l_lane[4];
#pragma unroll
  for (int r = 0; r < 4; ++r) l_lane[r] = 0.0f;
  float4v oacc = {0, 0, 0, 0};

  const int prow = (wu << 2) + 63 - lane;   // PwS row for this lane's delta (r=0)
  const int i_base = i0 + (wu << 2);
  const unsigned short* qbase = &qh[((b * Tt + i_base) * Hh + h) * Dd];

  // PV fragment roles: wave wu -> i-tile (wu&1), d-tile (wu>>1)
  const int i16 = (wu & 1) << 4;        // A-operand i-tile base row in pS
  const int dt0 = wu >> 1;              // d-tile 0..3
  const int lm = lane & 15;
  const int kq = (lane >> 4) << 3;      // k (j) octet within 32-half
  const unsigned short* vTbase = &vT[((b * HKV + hkv) * 64) * 512];

  for (int jt0 = 0; jt0 <= i0 + 31; jt0 += 64) {
    __syncthreads();   // guards PwS restage + pS rewrite vs prior-iter reads
    {
      // stage 95 rows x 64 fp16 = 760 uint4 slots with 512 threads
      const int pb0 = h * 1023 + (i0 - jt0) + 448;
      int r0 = t >> 3, c0 = (t & 7) << 3;
      *(uint4*)&PwS[r0][c0] = *(const uint4*)&Pwh[(pb0 + r0) * 64 + c0];
      int s2 = t + 512;
      if (s2 < 760) {
        int r2 = s2 >> 3, c2 = (s2 & 7) << 3;
        *(uint4*)&PwS[r2][c2] = *(const uint4*)&Pwh[(pb0 + r2) * 64 + c2];
      }
    }
    uint4 kr[8];
    {
      const uint4* kp = (const uint4*)&kh[((b * Tt + jt0 + lane) * HKV + hkv) * Dd];
#pragma unroll
      for (int c = 0; c < 8; ++c) kr[c] = kp[c];
    }
    __syncthreads();   // PwS ready

    // ---- score phase: lane = j; q broadcast (uniform), Pw from LDS, K regs ----
    const int j = jt0 + lane;
#pragma unroll
    for (int r = 0; r < 4; ++r) {
      const uint4* qp = (const uint4*)&qbase[r * (Hh * Dd)];  // wave-uniform
      float sr = 0.0f;
#pragma unroll
      for (int ch = 0; ch < 8; ++ch) {
        uint4 qu = qp[ch];
        uint4 pu = *(uint4*)&PwS[prow + r][ch << 3];
        sr = fdot2(u2h(qu.x) * u2h(pu.x), u2h(kr[ch].x), sr);
        sr = fdot2(u2h(qu.y) * u2h(pu.y), u2h(kr[ch].y), sr);
        sr = fdot2(u2h(qu.z) * u2h(pu.z), u2h(kr[ch].z), sr);
        sr = fdot2(u2h(qu.w) * u2h(pu.w), u2h(kr[ch].w), sr);
      }
      float sv = (j <= i_base + r) ? sr * 0.125f : -1e30f;
      float p = __expf(sv - 6.0f);   // fixed shift: exact softmax, no reduce
      l_lane[r] += p;
      pS[(wu << 2) + r][lane] = (__fp16)p;   // b16 store, 2-way banks
    }
    __syncthreads();   // pS ready for all waves

    // ---- PV phase: MFMA f16, A from pS, B from vT (global, L1/L2-hot) ----
    half8 a0 = *(half8*)&pS[i16 + lm][kq];
    half8 a1 = *(half8*)&pS[i16 + lm][kq + 32];
    const unsigned short* vp = vTbase + ((dt0 << 4) + lm) * 512 + jt0 + kq;
    half8 b0 = *(const half8*)&vp[0];
    half8 b1 = *(const half8*)&vp[32];
    oacc = __builtin_amdgcn_mfma_f32_16x16x32_f16(a0, b0, oacc, 0, 0, 0);
    oacc = __builtin_amdgcn_mfma_f32_16x16x32_f16(a1, b1, oacc, 0, 0, 0);
  }

  // final l reduction (once), shared via lS (score rows != C-layout rows)
#pragma unroll
  for (int r = 0; r < 4; ++r) {
    float lr = wave_reduce_sum(l_lane[r]);
    if (lane == r) lS[(wu << 2) + r] = lr;
  }
  __syncthreads();

  // epilogue: C layout — row = i16 + quad*4 + reg, col = d-tile*16 + lm
  const int d = (dt0 << 4) + lm;
#pragma unroll
  for (int r = 0; r < 4; ++r) {
    const int irow = i16 + ((lane >> 4) << 2) + r;
    const float val = oacc[r] / lS[irow];
    __hip_bfloat16 hv = __float2bfloat16(val);
    yb[((b * Tt + i0 + irow) * Hh + h) * Dd + d] = *(unsigned short*)&hv;
  }
}

extern "C" void kernel_launch(void* const* d_in, const int* in_sizes, int n_in,
                              void* d_out, int out_size, void* d_ws, size_t ws_size,
                              hipStream_t stream) {
  const float* x     = (const float*)d_in[0];
  const float* Wq    = (const float*)d_in[1];
  const float* Wk    = (const float*)d_in[2];
  const float* Wv    = (const float*)d_in[3];
  const float* Wproj = (const float*)d_in[4];
  const float* P     = (const float*)d_in[5];
  const float* sigma = (const float*)d_in[6];
  float* out = (float*)d_out;

  float* ws = (float*)d_ws;
  unsigned short* qh  = (unsigned short*)ws;                // 2,097,152 h = 1,048,576 f
  unsigned short* kh  = (unsigned short*)(ws + 1048576);    // 1,048,576 h = 524,288 f
  unsigned short* vT  = (unsigned short*)(ws + 1572864);    // 1,048,576 h = 524,288 f (transposed)
  unsigned short* Pwh = (unsigned short*)(ws + 2097152);    // 523,776 h -> 262,144 f
  unsigned short* xb  = (unsigned short*)(ws + 2359296);    // 2M bf16 = 1,048,576 f
  unsigned short* yb  = xb;                                 // alias: xb dead after qkv_mfma
  unsigned short* Wtq = (unsigned short*)(ws + 3407872);    // 524,288 h = 262,144 f
  unsigned short* Wtp = (unsigned short*)(ws + 3670016);    // 262,144 h = 131,072 f

  prep<<<dim3(3262), 256, 0, stream>>>(x, Wq, Wk, Wv, Wproj, P, sigma,
                                       xb, Wtq, Wtp, Pwh);
  qkv_mfma<<<dim3(64, 16), 256, 0, stream>>>(xb, Wtq, qh, kh, vT);
  attn<<<dim3(64, 16), 512, 0, stream>>>(qh, kh, vT, Pwh, yb);
  proj_mfma<<<dim3(64, 8), 256, 0, stream>>>(yb, Wtp, out);
}

// Round 2
// 148.431 us; speedup vs baseline: 1.0471x; 1.0471x over previous
//
#include <hip/hip_runtime.h>
#include <hip/hip_bf16.h>
#include <math.h>

#define Bb 8
#define Tt 512
#define Cc 512
#define Hh 8
#define HKV 4
#define Dd 64

typedef __attribute__((ext_vector_type(8))) short short8;
typedef __attribute__((ext_vector_type(4))) float float4v;
typedef __attribute__((ext_vector_type(2))) __fp16 h2;   // matches cvt_pkrtz return
typedef __attribute__((ext_vector_type(8))) __fp16 half8; // f16 MFMA fragment

__device__ __forceinline__ h2 u2h(unsigned u) {
  union { unsigned u; h2 h; } x; x.u = u; return x.h;
}
__device__ __forceinline__ unsigned h2u(h2 h) {
  union { h2 h; unsigned u; } x; x.h = h; return x.u;
}
__device__ __forceinline__ float fdot2(h2 a, h2 b, float c) {
#if __has_builtin(__builtin_amdgcn_fdot2)
  return __builtin_amdgcn_fdot2(a, b, c, false);
#else
  return fmaf((float)a.x, (float)b.x, fmaf((float)a.y, (float)b.y, c));
#endif
}

__device__ __forceinline__ float wave_reduce_sum(float v) {
#pragma unroll
  for (int off = 32; off > 0; off >>= 1) v += __shfl_xor(v, off, 64);
  return v;
}
__device__ __forceinline__ unsigned pack_bf2(float a, float b) {
  __hip_bfloat162 h = __float22bfloat162_rn(make_float2(a, b));
  return *(unsigned*)&h;
}

// ---------------- fused prep: conv_x | conv_w | build_pw (by block range) ----------------
__global__ __launch_bounds__(256) void prep(
    const float* __restrict__ x, const float* __restrict__ Wq,
    const float* __restrict__ Wk, const float* __restrict__ Wv,
    const float* __restrict__ Wp, const float* __restrict__ P,
    const float* __restrict__ sigma,
    unsigned short* __restrict__ xb, unsigned short* __restrict__ Wtq,
    unsigned short* __restrict__ Wtp, unsigned short* __restrict__ Pwh) {
  const int bid = blockIdx.x;
  const int t = threadIdx.x;
  if (bid < 1024) {
    int i = (bid * 256 + t) * 8;
    float4 f0 = *(const float4*)&x[i];
    float4 f1 = *(const float4*)&x[i + 4];
    unsigned u[4] = {pack_bf2(f0.x, f0.y), pack_bf2(f0.z, f0.w),
                     pack_bf2(f1.x, f1.y), pack_bf2(f1.z, f1.w)};
    *(uint4*)&xb[i] = *(uint4*)u;
  } else if (bid < 1216) {
    __shared__ float Ts[64][65];
    const int bx = bid - 1024;
    const int k0 = (bx & 7) << 6;
    const int n0 = (bx >> 3) << 6;
    const float* src; int ld, nc0; unsigned short* dst; int ndst;
    if (n0 < 512)       { src = Wq; ld = 512; nc0 = n0;        dst = Wtq; ndst = n0; }
    else if (n0 < 768)  { src = Wk; ld = 256; nc0 = n0 - 512;  dst = Wtq; ndst = n0; }
    else if (n0 < 1024) { src = Wv; ld = 256; nc0 = n0 - 768;  dst = Wtq; ndst = n0; }
    else                { src = Wp; ld = 512; nc0 = n0 - 1024; dst = Wtp; ndst = n0 - 1024; }
    const int r = t >> 4, c4 = (t & 15) << 2;
#pragma unroll
    for (int rr = 0; rr < 4; ++rr) {
      int row = (rr << 4) + r;
      float4 f = *(const float4*)&src[(k0 + row) * ld + nc0 + c4];
      Ts[row][c4] = f.x; Ts[row][c4 + 1] = f.y;
      Ts[row][c4 + 2] = f.z; Ts[row][c4 + 3] = f.w;
    }
    __syncthreads();
#pragma unroll
    for (int rr = 0; rr < 4; ++rr) {
      int nr = (rr << 4) + r;
      unsigned u0 = pack_bf2(Ts[c4][nr], Ts[c4 + 1][nr]);
      unsigned u1 = pack_bf2(Ts[c4 + 2][nr], Ts[c4 + 3][nr]);
      *(uint2*)&dst[(ndst + nr) * 512 + k0 + c4] = make_uint2(u0, u1);
    }
  } else {
    int idx = (bid - 1216) * 256 + t;
    int d = idx & 63;
    int rem = idx >> 6;
    int dd = rem % 1023;
    int h = rem / 1023;
    float s = fabsf(sigma[h]) + 1e-6f;
    float delta = (float)(dd - 511);
    float dt = 128.0f * tanhf(delta / s) + 128.0f;
    float lo = floorf(dt);
    int ilo = (int)lo;
    float frac = dt - lo;
    ilo = max(0, min(ilo, 256));
    int ihi = min(ilo + 1, 256);
    const float* Pb = P + h * 257 * 64;
    float val = (1.0f - frac) * Pb[ilo * 64 + d] + frac * Pb[ihi * 64 + d];
    __fp16 hv = (__fp16)val;
    Pwh[idx] = *(unsigned short*)&hv;
  }
}

// ---------------- QKV MFMA GEMM: 64x64 tile, padded LDS; v emitted TRANSPOSED ----------------
__global__ __launch_bounds__(256) void qkv_mfma(
    const unsigned short* __restrict__ xb, const unsigned short* __restrict__ Wt,
    unsigned short* __restrict__ qh, unsigned short* __restrict__ kh,
    unsigned short* __restrict__ vT) {
  __shared__ unsigned short As[64][72];
  __shared__ unsigned short Bs[64][72];
  const int m0 = blockIdx.x * 64;
  const int n0 = blockIdx.y * 64;
  const int t = threadIdx.x;
  const int w = t >> 6, lane = t & 63;
  const int srow = t >> 2, sc = (t & 3) << 4;
  float4v acc[4] = {{0,0,0,0},{0,0,0,0},{0,0,0,0},{0,0,0,0}};
  for (int k0 = 0; k0 < 512; k0 += 64) {
    uint4 a0 = *(const uint4*)&xb[(m0 + srow) * 512 + k0 + sc];
    uint4 a1 = *(const uint4*)&xb[(m0 + srow) * 512 + k0 + sc + 8];
    uint4 b0 = *(const uint4*)&Wt[(n0 + srow) * 512 + k0 + sc];
    uint4 b1 = *(const uint4*)&Wt[(n0 + srow) * 512 + k0 + sc + 8];
    __syncthreads();
    *(uint4*)&As[srow][sc] = a0; *(uint4*)&As[srow][sc + 8] = a1;
    *(uint4*)&Bs[srow][sc] = b0; *(uint4*)&Bs[srow][sc + 8] = b1;
    __syncthreads();
    const int ml = (w << 4) + (lane & 15);
    const int kq = (lane >> 4) << 3;
    short8 aF0 = *(short8*)&As[ml][kq];
    short8 aF1 = *(short8*)&As[ml][kq + 32];
#pragma unroll
    for (int nt = 0; nt < 4; ++nt) {
      const int nl = (nt << 4) + (lane & 15);
      short8 bF0 = *(short8*)&Bs[nl][kq];
      short8 bF1 = *(short8*)&Bs[nl][kq + 32];
      acc[nt] = __builtin_amdgcn_mfma_f32_16x16x32_bf16(aF0, bF0, acc[nt], 0, 0, 0);
      acc[nt] = __builtin_amdgcn_mfma_f32_16x16x32_bf16(aF1, bF1, acc[nt], 0, 0, 0);
    }
  }
  const int lane15 = lane & 15;
  const int rowbase = m0 + (w << 4) + ((lane >> 4) << 2);
  if (n0 < 768) {
    // q or k head: fused RMS-norm over the 64-wide head (= this n-tile)
#pragma unroll
    for (int r = 0; r < 4; ++r) {
      float ss = 0.0f;
#pragma unroll
      for (int nt = 0; nt < 4; ++nt) ss = fmaf(acc[nt][r], acc[nt][r], ss);
#pragma unroll
      for (int off = 1; off < 16; off <<= 1) ss += __shfl_xor(ss, off, 64);
      float sc2 = 8.0f * rsqrtf(ss + 1e-6f);
      const int row = rowbase + r;
      if (n0 < 512) {
        const int h = n0 >> 6;
#pragma unroll
        for (int nt = 0; nt < 4; ++nt) {
          __fp16 hv = (__fp16)(acc[nt][r] * sc2);
          qh[(row * Hh + h) * Dd + (nt << 4) + lane15] = *(unsigned short*)&hv;
        }
      } else {
        const int hkv = (n0 - 512) >> 6;
#pragma unroll
        for (int nt = 0; nt < 4; ++nt) {
          __fp16 hv = (__fp16)(acc[nt][r] * sc2);
          kh[(row * HKV + hkv) * Dd + (nt << 4) + lane15] = *(unsigned short*)&hv;
        }
      }
    }
  } else {
    // v transposed: vT[((b*HKV+hkv)*64 + d)*512 + t], 4 consecutive t per store
    const int hkv = (n0 - 768) >> 6;
    const int bb = rowbase >> 9;       // batch (64-row tile is within one b)
    const int trow = rowbase & 511;
#pragma unroll
    for (int nt = 0; nt < 4; ++nt) {
      const int d = (nt << 4) + lane15;
      unsigned u0 = h2u(__builtin_amdgcn_cvt_pkrtz(acc[nt][0], acc[nt][1]));
      unsigned u1 = h2u(__builtin_amdgcn_cvt_pkrtz(acc[nt][2], acc[nt][3]));
      *(uint2*)&vT[((bb * HKV + hkv) * 64 + d) * 512 + trow] = make_uint2(u0, u1);
    }
  }
}

// ---------------- Proj MFMA GEMM: 64x64 tile, padded LDS ----------------
__global__ __launch_bounds__(256) void proj_mfma(
    const unsigned short* __restrict__ yb, const unsigned short* __restrict__ Wt,
    float* __restrict__ out) {
  __shared__ unsigned short As[64][72];
  __shared__ unsigned short Bs[64][72];
  const int m0 = blockIdx.x * 64;
  const int n0 = blockIdx.y * 64;
  const int t = threadIdx.x;
  const int w = t >> 6, lane = t & 63;
  const int srow = t >> 2, sc = (t & 3) << 4;
  float4v acc[4] = {{0,0,0,0},{0,0,0,0},{0,0,0,0},{0,0,0,0}};
  for (int k0 = 0; k0 < 512; k0 += 64) {
    uint4 a0 = *(const uint4*)&yb[(m0 + srow) * 512 + k0 + sc];
    uint4 a1 = *(const uint4*)&yb[(m0 + srow) * 512 + k0 + sc + 8];
    uint4 b0 = *(const uint4*)&Wt[(n0 + srow) * 512 + k0 + sc];
    uint4 b1 = *(const uint4*)&Wt[(n0 + srow) * 512 + k0 + sc + 8];
    __syncthreads();
    *(uint4*)&As[srow][sc] = a0; *(uint4*)&As[srow][sc + 8] = a1;
    *(uint4*)&Bs[srow][sc] = b0; *(uint4*)&Bs[srow][sc + 8] = b1;
    __syncthreads();
    const int ml = (w << 4) + (lane & 15);
    const int kq = (lane >> 4) << 3;
    short8 aF0 = *(short8*)&As[ml][kq];
    short8 aF1 = *(short8*)&As[ml][kq + 32];
#pragma unroll
    for (int nt = 0; nt < 4; ++nt) {
      const int nl = (nt << 4) + (lane & 15);
      short8 bF0 = *(short8*)&Bs[nl][kq];
      short8 bF1 = *(short8*)&Bs[nl][kq + 32];
      acc[nt] = __builtin_amdgcn_mfma_f32_16x16x32_bf16(aF0, bF0, acc[nt], 0, 0, 0);
      acc[nt] = __builtin_amdgcn_mfma_f32_16x16x32_bf16(aF1, bF1, acc[nt], 0, 0, 0);
    }
  }
#pragma unroll
  for (int nt = 0; nt < 4; ++nt) {
    int col = n0 + (nt << 4) + (lane & 15);
#pragma unroll
    for (int r = 0; r < 4; ++r) {
      int row = m0 + (w << 4) + ((lane >> 4) << 2) + r;
      out[row * 512 + col] = acc[nt][r];
    }
  }
}

// ---------------- Attention v11: 16-row i-tiles, 2048 blocks for occupancy ----------------
// v9: 1024 blk x 256thr = exactly 4 blk/CU (grid-limited, Occ 33%, VALUBusy 52%).
// v10: 512thr + launch_bounds(512,8) -> VGPR capped at 32 -> massive scratch spill
//      (WRITE_SIZE 4MB->35MB), VALUBusy 37%. Lesson: more blocks, not bigger blocks.
// v11: 256 threads (4 waves, default bounds like v9 -> ~56 VGPR, no spill),
//      i-tile 32->16 rows, grid 64x32 = 2048 blocks = 8 blk/CU = 32 waves/CU cap.
//      LDS shrinks to ~13.9KB (PwS window 79 rows, pS 16 rows) -> 8 blk/CU fits.
//      Each wave: 4 score rows + ONE 16x16 PV d-tile (dt = wave id).
__global__ __launch_bounds__(256) void attn(
    const unsigned short* __restrict__ qh, const unsigned short* __restrict__ kh,
    const unsigned short* __restrict__ vT, const unsigned short* __restrict__ Pwh,
    unsigned short* __restrict__ yb) {
  __shared__ __fp16 PwS[80][72];  // 79 rows used
  __shared__ __fp16 pS[16][72];   // padded: A-frag start bank -> 2-way
  __shared__ float lS[16];

  const int t = threadIdx.x;
  const int lane = t & 63;
  const int wu = __builtin_amdgcn_readfirstlane(t >> 6);  // 0..3
  const int bh = blockIdx.x;
  const int b = bh >> 3;
  const int h = bh & 7;
  const int hkv = h >> 1;
  const int i0 = 496 - blockIdx.y * 16;  // heavy blocks first

  float l_lane[4];
#pragma unroll
  for (int r = 0; r < 4; ++r) l_lane[r] = 0.0f;
  float4v oacc = {0, 0, 0, 0};

  const int prow = (wu << 2) + 63 - lane;   // PwS row for this lane's delta (r=0)
  const int i_base = i0 + (wu << 2);
  const unsigned short* qbase = &qh[((b * Tt + i_base) * Hh + h) * Dd];

  // PV fragment roles: wave wu owns d-tile wu of the 16x64 O tile
  const int dt0 = wu;
  const int lm = lane & 15;
  const int kq = (lane >> 4) << 3;      // k (j) octet within 32-half
  const unsigned short* vTbase = &vT[((b * HKV + hkv) * 64) * 512];

  for (int jt0 = 0; jt0 <= i0 + 15; jt0 += 64) {
    __syncthreads();   // guards PwS restage + pS rewrite vs prior-iter reads
    {
      // stage 79 rows x 64 fp16 = 632 uint4 slots with 256 threads (3 rounds)
      const int pb0 = h * 1023 + (i0 - jt0) + 448;
      int s = t;
#pragma unroll
      for (int rnd = 0; rnd < 3; ++rnd) {
        if (s < 632) {
          int r = s >> 3, c = (s & 7) << 3;
          *(uint4*)&PwS[r][c] = *(const uint4*)&Pwh[(pb0 + r) * 64 + c];
        }
        s += 256;
      }
    }
    uint4 kr[8];
    {
      const uint4* kp = (const uint4*)&kh[((b * Tt + jt0 + lane) * HKV + hkv) * Dd];
#pragma unroll
      for (int c = 0; c < 8; ++c) kr[c] = kp[c];
    }
    __syncthreads();   // PwS ready

    // ---- score phase: lane = j; q broadcast (uniform), Pw from LDS, K regs ----
    const int j = jt0 + lane;
#pragma unroll
    for (int r = 0; r < 4; ++r) {
      const uint4* qp = (const uint4*)&qbase[r * (Hh * Dd)];  // wave-uniform
      float sr = 0.0f;
#pragma unroll
      for (int ch = 0; ch < 8; ++ch) {
        uint4 qu = qp[ch];
        uint4 pu = *(uint4*)&PwS[prow + r][ch << 3];
        sr = fdot2(u2h(qu.x) * u2h(pu.x), u2h(kr[ch].x), sr);
        sr = fdot2(u2h(qu.y) * u2h(pu.y), u2h(kr[ch].y), sr);
        sr = fdot2(u2h(qu.z) * u2h(pu.z), u2h(kr[ch].z), sr);
        sr = fdot2(u2h(qu.w) * u2h(pu.w), u2h(kr[ch].w), sr);
      }
      float sv = (j <= i_base + r) ? sr * 0.125f : -1e30f;
      float p = __expf(sv - 6.0f);   // fixed shift: exact softmax, no reduce
      l_lane[r] += p;
      pS[(wu << 2) + r][lane] = (__fp16)p;   // b16 store, 2-way banks
    }
    __syncthreads();   // pS ready for all waves

    // ---- PV phase: MFMA f16, A from pS (all 16 rows), B from vT (L1/L2-hot) ----
    half8 a0 = *(half8*)&pS[lm][kq];
    half8 a1 = *(half8*)&pS[lm][kq + 32];
    const unsigned short* vp = vTbase + ((dt0 << 4) + lm) * 512 + jt0 + kq;
    half8 b0 = *(const half8*)&vp[0];
    half8 b1 = *(const half8*)&vp[32];
    oacc = __builtin_amdgcn_mfma_f32_16x16x32_f16(a0, b0, oacc, 0, 0, 0);
    oacc = __builtin_amdgcn_mfma_f32_16x16x32_f16(a1, b1, oacc, 0, 0, 0);
  }

  // final l reduction (once), shared via lS (score rows != C-layout rows)
#pragma unroll
  for (int r = 0; r < 4; ++r) {
    float lr = wave_reduce_sum(l_lane[r]);
    if (lane == r) lS[(wu << 2) + r] = lr;
  }
  __syncthreads();

  // epilogue: C layout — row = quad*4 + reg, col = d-tile*16 + lm
  const int d = (dt0 << 4) + lm;
#pragma unroll
  for (int r = 0; r < 4; ++r) {
    const int irow = ((lane >> 4) << 2) + r;
    const float val = oacc[r] / lS[irow];
    __hip_bfloat16 hv = __float2bfloat16(val);
    yb[((b * Tt + i0 + irow) * Hh + h) * Dd + d] = *(unsigned short*)&hv;
  }
}

extern "C" void kernel_launch(void* const* d_in, const int* in_sizes, int n_in,
                              void* d_out, int out_size, void* d_ws, size_t ws_size,
                              hipStream_t stream) {
  const float* x     = (const float*)d_in[0];
  const float* Wq    = (const float*)d_in[1];
  const float* Wk    = (const float*)d_in[2];
  const float* Wv    = (const float*)d_in[3];
  const float* Wproj = (const float*)d_in[4];
  const float* P     = (const float*)d_in[5];
  const float* sigma = (const float*)d_in[6];
  float* out = (float*)d_out;

  float* ws = (float*)d_ws;
  unsigned short* qh  = (unsigned short*)ws;                // 2,097,152 h = 1,048,576 f
  unsigned short* kh  = (unsigned short*)(ws + 1048576);    // 1,048,576 h = 524,288 f
  unsigned short* vT  = (unsigned short*)(ws + 1572864);    // 1,048,576 h = 524,288 f (transposed)
  unsigned short* Pwh = (unsigned short*)(ws + 2097152);    // 523,776 h -> 262,144 f
  unsigned short* xb  = (unsigned short*)(ws + 2359296);    // 2M bf16 = 1,048,576 f
  unsigned short* yb  = xb;                                 // alias: xb dead after qkv_mfma
  unsigned short* Wtq = (unsigned short*)(ws + 3407872);    // 524,288 h = 262,144 f
  unsigned short* Wtp = (unsigned short*)(ws + 3670016);    // 262,144 h = 131,072 f

  prep<<<dim3(3262), 256, 0, stream>>>(x, Wq, Wk, Wv, Wproj, P, sigma,
                                       xb, Wtq, Wtp, Pwh);
  qkv_mfma<<<dim3(64, 16), 256, 0, stream>>>(xb, Wtq, qh, kh, vT);
  attn<<<dim3(64, 32), 256, 0, stream>>>(qh, kh, vT, Pwh, yb);
  proj_mfma<<<dim3(64, 8), 256, 0, stream>>>(yb, Wtp, out);
}

// Round 4
// 139.929 us; speedup vs baseline: 1.1107x; 1.0608x over previous
//
#include <hip/hip_runtime.h>
#include <hip/hip_bf16.h>
#include <math.h>

#define Bb 8
#define Tt 512
#define Cc 512
#define Hh 8
#define HKV 4
#define Dd 64

typedef __attribute__((ext_vector_type(8))) short short8;
typedef __attribute__((ext_vector_type(4))) float float4v;
typedef __attribute__((ext_vector_type(2))) __fp16 h2;   // matches cvt_pkrtz return
typedef __attribute__((ext_vector_type(8))) __fp16 half8; // f16 MFMA fragment

__device__ __forceinline__ h2 u2h(unsigned u) {
  union { unsigned u; h2 h; } x; x.u = u; return x.h;
}
__device__ __forceinline__ unsigned h2u(h2 h) {
  union { h2 h; unsigned u; } x; x.h = h; return x.u;
}
__device__ __forceinline__ float fdot2(h2 a, h2 b, float c) {
#if __has_builtin(__builtin_amdgcn_fdot2)
  return __builtin_amdgcn_fdot2(a, b, c, false);
#else
  return fmaf((float)a.x, (float)b.x, fmaf((float)a.y, (float)b.y, c));
#endif
}

__device__ __forceinline__ float wave_reduce_sum(float v) {
#pragma unroll
  for (int off = 32; off > 0; off >>= 1) v += __shfl_xor(v, off, 64);
  return v;
}
__device__ __forceinline__ unsigned pack_bf2(float a, float b) {
  __hip_bfloat162 h = __float22bfloat162_rn(make_float2(a, b));
  return *(unsigned*)&h;
}

// ---------------- fused prep: conv_x | conv_w | build_pw (by block range) ----------------
__global__ __launch_bounds__(256) void prep(
    const float* __restrict__ x, const float* __restrict__ Wq,
    const float* __restrict__ Wk, const float* __restrict__ Wv,
    const float* __restrict__ Wp, const float* __restrict__ P,
    const float* __restrict__ sigma,
    unsigned short* __restrict__ xb, unsigned short* __restrict__ Wtq,
    unsigned short* __restrict__ Wtp, unsigned short* __restrict__ Pwh) {
  const int bid = blockIdx.x;
  const int t = threadIdx.x;
  if (bid < 1024) {
    int i = (bid * 256 + t) * 8;
    float4 f0 = *(const float4*)&x[i];
    float4 f1 = *(const float4*)&x[i + 4];
    unsigned u[4] = {pack_bf2(f0.x, f0.y), pack_bf2(f0.z, f0.w),
                     pack_bf2(f1.x, f1.y), pack_bf2(f1.z, f1.w)};
    *(uint4*)&xb[i] = *(uint4*)u;
  } else if (bid < 1216) {
    __shared__ float Ts[64][65];
    const int bx = bid - 1024;
    const int k0 = (bx & 7) << 6;
    const int n0 = (bx >> 3) << 6;
    const float* src; int ld, nc0; unsigned short* dst; int ndst;
    if (n0 < 512)       { src = Wq; ld = 512; nc0 = n0;        dst = Wtq; ndst = n0; }
    else if (n0 < 768)  { src = Wk; ld = 256; nc0 = n0 - 512;  dst = Wtq; ndst = n0; }
    else if (n0 < 1024) { src = Wv; ld = 256; nc0 = n0 - 768;  dst = Wtq; ndst = n0; }
    else                { src = Wp; ld = 512; nc0 = n0 - 1024; dst = Wtp; ndst = n0 - 1024; }
    const int r = t >> 4, c4 = (t & 15) << 2;
#pragma unroll
    for (int rr = 0; rr < 4; ++rr) {
      int row = (rr << 4) + r;
      float4 f = *(const float4*)&src[(k0 + row) * ld + nc0 + c4];
      Ts[row][c4] = f.x; Ts[row][c4 + 1] = f.y;
      Ts[row][c4 + 2] = f.z; Ts[row][c4 + 3] = f.w;
    }
    __syncthreads();
#pragma unroll
    for (int rr = 0; rr < 4; ++rr) {
      int nr = (rr << 4) + r;
      unsigned u0 = pack_bf2(Ts[c4][nr], Ts[c4 + 1][nr]);
      unsigned u1 = pack_bf2(Ts[c4 + 2][nr], Ts[c4 + 3][nr]);
      *(uint2*)&dst[(ndst + nr) * 512 + k0 + c4] = make_uint2(u0, u1);
    }
  } else {
    int idx = (bid - 1216) * 256 + t;
    int d = idx & 63;
    int rem = idx >> 6;
    int dd = rem % 1023;
    int h = rem / 1023;
    float s = fabsf(sigma[h]) + 1e-6f;
    float delta = (float)(dd - 511);
    float dt = 128.0f * tanhf(delta / s) + 128.0f;
    float lo = floorf(dt);
    int ilo = (int)lo;
    float frac = dt - lo;
    ilo = max(0, min(ilo, 256));
    int ihi = min(ilo + 1, 256);
    const float* Pb = P + h * 257 * 64;
    float val = (1.0f - frac) * Pb[ilo * 64 + d] + frac * Pb[ihi * 64 + d];
    __fp16 hv = (__fp16)val;
    Pwh[idx] = *(unsigned short*)&hv;
  }
}

// ---------------- QKV MFMA GEMM: 64x64 tile, padded LDS; v emitted TRANSPOSED ----------------
__global__ __launch_bounds__(256) void qkv_mfma(
    const unsigned short* __restrict__ xb, const unsigned short* __restrict__ Wt,
    unsigned short* __restrict__ qh, unsigned short* __restrict__ kh,
    unsigned short* __restrict__ vT) {
  __shared__ unsigned short As[64][72];
  __shared__ unsigned short Bs[64][72];
  const int m0 = blockIdx.x * 64;
  const int n0 = blockIdx.y * 64;
  const int t = threadIdx.x;
  const int w = t >> 6, lane = t & 63;
  const int srow = t >> 2, sc = (t & 3) << 4;
  float4v acc[4] = {{0,0,0,0},{0,0,0,0},{0,0,0,0},{0,0,0,0}};
  for (int k0 = 0; k0 < 512; k0 += 64) {
    uint4 a0 = *(const uint4*)&xb[(m0 + srow) * 512 + k0 + sc];
    uint4 a1 = *(const uint4*)&xb[(m0 + srow) * 512 + k0 + sc + 8];
    uint4 b0 = *(const uint4*)&Wt[(n0 + srow) * 512 + k0 + sc];
    uint4 b1 = *(const uint4*)&Wt[(n0 + srow) * 512 + k0 + sc + 8];
    __syncthreads();
    *(uint4*)&As[srow][sc] = a0; *(uint4*)&As[srow][sc + 8] = a1;
    *(uint4*)&Bs[srow][sc] = b0; *(uint4*)&Bs[srow][sc + 8] = b1;
    __syncthreads();
    const int ml = (w << 4) + (lane & 15);
    const int kq = (lane >> 4) << 3;
    short8 aF0 = *(short8*)&As[ml][kq];
    short8 aF1 = *(short8*)&As[ml][kq + 32];
#pragma unroll
    for (int nt = 0; nt < 4; ++nt) {
      const int nl = (nt << 4) + (lane & 15);
      short8 bF0 = *(short8*)&Bs[nl][kq];
      short8 bF1 = *(short8*)&Bs[nl][kq + 32];
      acc[nt] = __builtin_amdgcn_mfma_f32_16x16x32_bf16(aF0, bF0, acc[nt], 0, 0, 0);
      acc[nt] = __builtin_amdgcn_mfma_f32_16x16x32_bf16(aF1, bF1, acc[nt], 0, 0, 0);
    }
  }
  const int lane15 = lane & 15;
  const int rowbase = m0 + (w << 4) + ((lane >> 4) << 2);
  if (n0 < 768) {
    // q or k head: fused RMS-norm over the 64-wide head (= this n-tile)
#pragma unroll
    for (int r = 0; r < 4; ++r) {
      float ss = 0.0f;
#pragma unroll
      for (int nt = 0; nt < 4; ++nt) ss = fmaf(acc[nt][r], acc[nt][r], ss);
#pragma unroll
      for (int off = 1; off < 16; off <<= 1) ss += __shfl_xor(ss, off, 64);
      float sc2 = 8.0f * rsqrtf(ss + 1e-6f);
      const int row = rowbase + r;
      if (n0 < 512) {
        const int h = n0 >> 6;
#pragma unroll
        for (int nt = 0; nt < 4; ++nt) {
          __fp16 hv = (__fp16)(acc[nt][r] * sc2);
          qh[(row * Hh + h) * Dd + (nt << 4) + lane15] = *(unsigned short*)&hv;
        }
      } else {
        const int hkv = (n0 - 512) >> 6;
#pragma unroll
        for (int nt = 0; nt < 4; ++nt) {
          __fp16 hv = (__fp16)(acc[nt][r] * sc2);
          kh[(row * HKV + hkv) * Dd + (nt << 4) + lane15] = *(unsigned short*)&hv;
        }
      }
    }
  } else {
    // v transposed: vT[((b*HKV+hkv)*64 + d)*512 + t], 4 consecutive t per store
    const int hkv = (n0 - 768) >> 6;
    const int bb = rowbase >> 9;       // batch (64-row tile is within one b)
    const int trow = rowbase & 511;
#pragma unroll
    for (int nt = 0; nt < 4; ++nt) {
      const int d = (nt << 4) + lane15;
      unsigned u0 = h2u(__builtin_amdgcn_cvt_pkrtz(acc[nt][0], acc[nt][1]));
      unsigned u1 = h2u(__builtin_amdgcn_cvt_pkrtz(acc[nt][2], acc[nt][3]));
      *(uint2*)&vT[((bb * HKV + hkv) * 64 + d) * 512 + trow] = make_uint2(u0, u1);
    }
  }
}

// ---------------- Proj MFMA GEMM: 64x64 tile, padded LDS ----------------
__global__ __launch_bounds__(256) void proj_mfma(
    const unsigned short* __restrict__ yb, const unsigned short* __restrict__ Wt,
    float* __restrict__ out) {
  __shared__ unsigned short As[64][72];
  __shared__ unsigned short Bs[64][72];
  const int m0 = blockIdx.x * 64;
  const int n0 = blockIdx.y * 64;
  const int t = threadIdx.x;
  const int w = t >> 6, lane = t & 63;
  const int srow = t >> 2, sc = (t & 3) << 4;
  float4v acc[4] = {{0,0,0,0},{0,0,0,0},{0,0,0,0},{0,0,0,0}};
  for (int k0 = 0; k0 < 512; k0 += 64) {
    uint4 a0 = *(const uint4*)&yb[(m0 + srow) * 512 + k0 + sc];
    uint4 a1 = *(const uint4*)&yb[(m0 + srow) * 512 + k0 + sc + 8];
    uint4 b0 = *(const uint4*)&Wt[(n0 + srow) * 512 + k0 + sc];
    uint4 b1 = *(const uint4*)&Wt[(n0 + srow) * 512 + k0 + sc + 8];
    __syncthreads();
    *(uint4*)&As[srow][sc] = a0; *(uint4*)&As[srow][sc + 8] = a1;
    *(uint4*)&Bs[srow][sc] = b0; *(uint4*)&Bs[srow][sc + 8] = b1;
    __syncthreads();
    const int ml = (w << 4) + (lane & 15);
    const int kq = (lane >> 4) << 3;
    short8 aF0 = *(short8*)&As[ml][kq];
    short8 aF1 = *(short8*)&As[ml][kq + 32];
#pragma unroll
    for (int nt = 0; nt < 4; ++nt) {
      const int nl = (nt << 4) + (lane & 15);
      short8 bF0 = *(short8*)&Bs[nl][kq];
      short8 bF1 = *(short8*)&Bs[nl][kq + 32];
      acc[nt] = __builtin_amdgcn_mfma_f32_16x16x32_bf16(aF0, bF0, acc[nt], 0, 0, 0);
      acc[nt] = __builtin_amdgcn_mfma_f32_16x16x32_bf16(aF1, bF1, acc[nt], 0, 0, 0);
    }
  }
#pragma unroll
  for (int nt = 0; nt < 4; ++nt) {
    int col = n0 + (nt << 4) + (lane & 15);
#pragma unroll
    for (int r = 0; r < 4; ++r) {
      int row = m0 + (w << 4) + ((lane >> 4) << 2) + r;
      out[row * 512 + col] = acc[nt][r];
    }
  }
}

// ---------------- Attention v12: v9 geometry + 1-barrier pipeline + balance ----------------
// v9 (49.4us): 3 barriers/iter, staging latency exposed, CU load skew 14..20 iter-units.
// v10 lesson: never cap VGPR. v11 lesson: fixed per-iter overhead F ~30%; halving tiles
// pays F twice. v12 keeps v9 geometry (32-row tile, 1024 blk, 4 waves) and removes stalls:
//  - double-buffered PwS + pS -> ONE __syncthreads per j-tile iteration
//  - T14 async-stage: issue kr + Pw global loads early, PV(t-1) MFMAs hide latency,
//    LDS writes late, score last
//  - balanced i0 remap (nibble LUT 0x4567BA983210CDEF): co-resident blocks (y = b mod 4)
//    sum to equal work -> kills the 1.4x drain skew
__global__ __launch_bounds__(256) void attn(
    const unsigned short* __restrict__ qh, const unsigned short* __restrict__ kh,
    const unsigned short* __restrict__ vT, const unsigned short* __restrict__ Pwh,
    unsigned short* __restrict__ yb) {
  __shared__ __fp16 PwS[2][96][72];   // 27648 B
  __shared__ __fp16 pS[2][32][72];    //  9216 B
  __shared__ float lS[32];

  const int t = threadIdx.x;
  const int lane = t & 63;
  const int wu = __builtin_amdgcn_readfirstlane(t >> 6);
  const int bh = blockIdx.x;
  const int b = bh >> 3;
  const int h = bh & 7;
  const int hkv = h >> 1;
  // balanced tile assignment: i0/32 = nibble y of LUT; sets {b,b+4,b+8,b+12} sum 30
  const int i0 = (int)((0x4567BA983210CDEFull >> (blockIdx.y * 4)) & 15) * 32;
  const int nt = (i0 >> 6) + 1;   // = (i0+31)/64 + 1 for i0 multiple of 32

  float l_lane[8];
#pragma unroll
  for (int r = 0; r < 8; ++r) l_lane[r] = 0.0f;
  float4v oacc[2] = {{0, 0, 0, 0}, {0, 0, 0, 0}};

  const int prow = (wu << 3) + 63 - lane;
  const int i_base = i0 + (wu << 3);
  const unsigned short* qbase = &qh[((b * Tt + i_base) * Hh + h) * Dd];

  // PV fragment roles
  const int i16 = (wu & 1) << 4;        // A-operand i-tile base row in pS
  const int dt0 = (wu >> 1) << 1;       // first of 2 d-tiles
  const int lm = lane & 15;
  const int kq = (lane >> 4) << 3;      // k (j) octet within 32-half
  const unsigned short* vTbase = &vT[((b * HKV + hkv) * 64) * 512];

  // staging thread roles (95 rows x 64 fp16 per window)
  const int sjr = t >> 2, sdc = (t & 3) << 4;      // rows 0..63, 2x uint4
  const int spr2 = 64 + (t >> 3), sdc2 = (t & 7) << 3;  // rows 64..94, 1x uint4

  // ---- prologue: stage window 0 into buf 0, load kr(0) ----
  {
    const int pb0 = h * 1023 + i0 + 448;
    const unsigned short* pwp = &Pwh[(pb0 + sjr) * 64 + sdc];
    *(uint4*)&PwS[0][sjr][sdc]     = *(const uint4*)&pwp[0];
    *(uint4*)&PwS[0][sjr][sdc + 8] = *(const uint4*)&pwp[8];
    if (spr2 < 95)
      *(uint4*)&PwS[0][spr2][sdc2] = *(const uint4*)&Pwh[(pb0 + spr2) * 64 + sdc2];
  }
  uint4 kr[8];
  {
    const uint4* kp = (const uint4*)&kh[((b * Tt + lane) * HKV + hkv) * Dd];
#pragma unroll
    for (int c = 0; c < 8; ++c) kr[c] = kp[c];
  }
  __syncthreads();

  for (int tt = 0; tt < nt; ++tt) {
    const int jt0 = tt << 6;
    const int cb = tt & 1;

    // -- (1) issue next-tile K loads early (latency hidden under PV+score) --
    uint4 kr2[8];
    if (tt + 1 < nt) {
      const uint4* kp = (const uint4*)&kh[((b * Tt + jt0 + 64 + lane) * HKV + hkv) * Dd];
#pragma unroll
      for (int c = 0; c < 8; ++c) kr2[c] = kp[c];
    }
    // -- (2) issue next-window Pw loads into regs (write to LDS later: T14 split) --
    uint4 sw0, sw1, sw2;
    const bool do_stage = (tt + 1 < nt);
    if (do_stage) {
      const int pb0 = h * 1023 + (i0 - jt0 - 64) + 448;
      const unsigned short* pwp = &Pwh[(pb0 + sjr) * 64 + sdc];
      sw0 = *(const uint4*)&pwp[0];
      sw1 = *(const uint4*)&pwp[8];
      if (spr2 < 95) sw2 = *(const uint4*)&Pwh[(pb0 + spr2) * 64 + sdc2];
    }

    // -- (3) PV(tt-1): MFMAs overlap the in-flight global loads --
    if (tt > 0) {
      const int bp = cb ^ 1;
      const int jp = jt0 - 64;
      half8 a0 = *(half8*)&pS[bp][i16 + lm][kq];
      half8 a1 = *(half8*)&pS[bp][i16 + lm][kq + 32];
#pragma unroll
      for (int dd = 0; dd < 2; ++dd) {
        const unsigned short* vp = vTbase + (((dt0 + dd) << 4) + lm) * 512 + jp + kq;
        half8 b0 = *(const half8*)&vp[0];
        half8 b1 = *(const half8*)&vp[32];
        oacc[dd] = __builtin_amdgcn_mfma_f32_16x16x32_f16(a0, b0, oacc[dd], 0, 0, 0);
        oacc[dd] = __builtin_amdgcn_mfma_f32_16x16x32_f16(a1, b1, oacc[dd], 0, 0, 0);
      }
    }

    // -- (4) write staged Pw window to the other LDS buffer --
    if (do_stage) {
      const int sb = cb ^ 1;
      *(uint4*)&PwS[sb][sjr][sdc]     = sw0;
      *(uint4*)&PwS[sb][sjr][sdc + 8] = sw1;
      if (spr2 < 95) *(uint4*)&PwS[sb][spr2][sdc2] = sw2;
    }

    // -- (5) score(tt): lane = j; q broadcast (uniform), Pw from LDS buf cb, K regs --
    const int j = jt0 + lane;
#pragma unroll
    for (int r = 0; r < 8; ++r) {
      const uint4* qp = (const uint4*)&qbase[r * (Hh * Dd)];  // wave-uniform
      float sr = 0.0f;
#pragma unroll
      for (int ch = 0; ch < 8; ++ch) {
        uint4 qu = qp[ch];
        uint4 pu = *(uint4*)&PwS[cb][prow + r][ch << 3];
        sr = fdot2(u2h(qu.x) * u2h(pu.x), u2h(kr[ch].x), sr);
        sr = fdot2(u2h(qu.y) * u2h(pu.y), u2h(kr[ch].y), sr);
        sr = fdot2(u2h(qu.z) * u2h(pu.z), u2h(kr[ch].z), sr);
        sr = fdot2(u2h(qu.w) * u2h(pu.w), u2h(kr[ch].w), sr);
      }
      float sv = (j <= i_base + r) ? sr * 0.125f : -1e30f;
      float p = __expf(sv - 6.0f);   // fixed shift: exact softmax, no reduce
      l_lane[r] += p;
      pS[cb][(wu << 3) + r][lane] = (__fp16)p;
    }

    // -- (6) rotate kr, single barrier --
    if (tt + 1 < nt) {
#pragma unroll
      for (int c = 0; c < 8; ++c) kr[c] = kr2[c];
    }
    __syncthreads();
  }

  // ---- epilogue PV(nt-1) ----
  {
    const int bp = (nt - 1) & 1;
    const int jp = (nt - 1) << 6;
    half8 a0 = *(half8*)&pS[bp][i16 + lm][kq];
    half8 a1 = *(half8*)&pS[bp][i16 + lm][kq + 32];
#pragma unroll
    for (int dd = 0; dd < 2; ++dd) {
      const unsigned short* vp = vTbase + (((dt0 + dd) << 4) + lm) * 512 + jp + kq;
      half8 b0 = *(const half8*)&vp[0];
      half8 b1 = *(const half8*)&vp[32];
      oacc[dd] = __builtin_amdgcn_mfma_f32_16x16x32_f16(a0, b0, oacc[dd], 0, 0, 0);
      oacc[dd] = __builtin_amdgcn_mfma_f32_16x16x32_f16(a1, b1, oacc[dd], 0, 0, 0);
    }
  }

  // final l reduction (once), shared via lS (score rows != C-layout rows)
#pragma unroll
  for (int r = 0; r < 8; ++r) {
    float lr = wave_reduce_sum(l_lane[r]);
    if (lane == r) lS[(wu << 3) + r] = lr;
  }
  __syncthreads();

  // epilogue: C layout — row = i16 + quad*4 + reg, col = d-tile*16 + lm
#pragma unroll
  for (int dd = 0; dd < 2; ++dd) {
    const int d = ((dt0 + dd) << 4) + lm;
#pragma unroll
    for (int r = 0; r < 4; ++r) {
      const int irow = i16 + ((lane >> 4) << 2) + r;
      const float val = oacc[dd][r] / lS[irow];
      __hip_bfloat16 hv = __float2bfloat16(val);
      yb[((b * Tt + i0 + irow) * Hh + h) * Dd + d] = *(unsigned short*)&hv;
    }
  }
}

extern "C" void kernel_launch(void* const* d_in, const int* in_sizes, int n_in,
                              void* d_out, int out_size, void* d_ws, size_t ws_size,
                              hipStream_t stream) {
  const float* x     = (const float*)d_in[0];
  const float* Wq    = (const float*)d_in[1];
  const float* Wk    = (const float*)d_in[2];
  const float* Wv    = (const float*)d_in[3];
  const float* Wproj = (const float*)d_in[4];
  const float* P     = (const float*)d_in[5];
  const float* sigma = (const float*)d_in[6];
  float* out = (float*)d_out;

  float* ws = (float*)d_ws;
  unsigned short* qh  = (unsigned short*)ws;                // 2,097,152 h = 1,048,576 f
  unsigned short* kh  = (unsigned short*)(ws + 1048576);    // 1,048,576 h = 524,288 f
  unsigned short* vT  = (unsigned short*)(ws + 1572864);    // 1,048,576 h = 524,288 f (transposed)
  unsigned short* Pwh = (unsigned short*)(ws + 2097152);    // 523,776 h -> 262,144 f
  unsigned short* xb  = (unsigned short*)(ws + 2359296);    // 2M bf16 = 1,048,576 f
  unsigned short* yb  = xb;                                 // alias: xb dead after qkv_mfma
  unsigned short* Wtq = (unsigned short*)(ws + 3407872);    // 524,288 h = 262,144 f
  unsigned short* Wtp = (unsigned short*)(ws + 3670016);    // 262,144 h = 131,072 f

  prep<<<dim3(3262), 256, 0, stream>>>(x, Wq, Wk, Wv, Wproj, P, sigma,
                                       xb, Wtq, Wtp, Pwh);
  qkv_mfma<<<dim3(64, 16), 256, 0, stream>>>(xb, Wtq, qh, kh, vT);
  attn<<<dim3(64, 16), 256, 0, stream>>>(qh, kh, vT, Pwh, yb);
  proj_mfma<<<dim3(64, 8), 256, 0, stream>>>(yb, Wtp, out);
}

// Round 5
// 137.618 us; speedup vs baseline: 1.1294x; 1.0168x over previous
//
#include <hip/hip_runtime.h>
#include <hip/hip_bf16.h>
#include <math.h>

#define Bb 8
#define Tt 512
#define Cc 512
#define Hh 8
#define HKV 4
#define Dd 64

typedef __attribute__((ext_vector_type(8))) short short8;
typedef __attribute__((ext_vector_type(4))) float float4v;
typedef __attribute__((ext_vector_type(2))) __fp16 h2;   // matches cvt_pkrtz return
typedef __attribute__((ext_vector_type(8))) __fp16 half8; // f16 MFMA fragment

__device__ __forceinline__ h2 u2h(unsigned u) {
  union { unsigned u; h2 h; } x; x.u = u; return x.h;
}
__device__ __forceinline__ unsigned h2u(h2 h) {
  union { h2 h; unsigned u; } x; x.h = h; return x.u;
}
__device__ __forceinline__ float fdot2(h2 a, h2 b, float c) {
#if __has_builtin(__builtin_amdgcn_fdot2)
  return __builtin_amdgcn_fdot2(a, b, c, false);
#else
  return fmaf((float)a.x, (float)b.x, fmaf((float)a.y, (float)b.y, c));
#endif
}

__device__ __forceinline__ float wave_reduce_sum(float v) {
#pragma unroll
  for (int off = 32; off > 0; off >>= 1) v += __shfl_xor(v, off, 64);
  return v;
}
__device__ __forceinline__ unsigned pack_bf2(float a, float b) {
  __hip_bfloat162 h = __float22bfloat162_rn(make_float2(a, b));
  return *(unsigned*)&h;
}

// ---------------- fused prep: conv_x | conv_w | build_pw (by block range) ----------------
__global__ __launch_bounds__(256) void prep(
    const float* __restrict__ x, const float* __restrict__ Wq,
    const float* __restrict__ Wk, const float* __restrict__ Wv,
    const float* __restrict__ Wp, const float* __restrict__ P,
    const float* __restrict__ sigma,
    unsigned short* __restrict__ xb, unsigned short* __restrict__ Wtq,
    unsigned short* __restrict__ Wtp, unsigned short* __restrict__ Pwh) {
  const int bid = blockIdx.x;
  const int t = threadIdx.x;
  if (bid < 1024) {
    int i = (bid * 256 + t) * 8;
    float4 f0 = *(const float4*)&x[i];
    float4 f1 = *(const float4*)&x[i + 4];
    unsigned u[4] = {pack_bf2(f0.x, f0.y), pack_bf2(f0.z, f0.w),
                     pack_bf2(f1.x, f1.y), pack_bf2(f1.z, f1.w)};
    *(uint4*)&xb[i] = *(uint4*)u;
  } else if (bid < 1216) {
    __shared__ float Ts[64][65];
    const int bx = bid - 1024;
    const int k0 = (bx & 7) << 6;
    const int n0 = (bx >> 3) << 6;
    const float* src; int ld, nc0; unsigned short* dst; int ndst;
    if (n0 < 512)       { src = Wq; ld = 512; nc0 = n0;        dst = Wtq; ndst = n0; }
    else if (n0 < 768)  { src = Wk; ld = 256; nc0 = n0 - 512;  dst = Wtq; ndst = n0; }
    else if (n0 < 1024) { src = Wv; ld = 256; nc0 = n0 - 768;  dst = Wtq; ndst = n0; }
    else                { src = Wp; ld = 512; nc0 = n0 - 1024; dst = Wtp; ndst = n0 - 1024; }
    const int r = t >> 4, c4 = (t & 15) << 2;
#pragma unroll
    for (int rr = 0; rr < 4; ++rr) {
      int row = (rr << 4) + r;
      float4 f = *(const float4*)&src[(k0 + row) * ld + nc0 + c4];
      Ts[row][c4] = f.x; Ts[row][c4 + 1] = f.y;
      Ts[row][c4 + 2] = f.z; Ts[row][c4 + 3] = f.w;
    }
    __syncthreads();
#pragma unroll
    for (int rr = 0; rr < 4; ++rr) {
      int nr = (rr << 4) + r;
      unsigned u0 = pack_bf2(Ts[c4][nr], Ts[c4 + 1][nr]);
      unsigned u1 = pack_bf2(Ts[c4 + 2][nr], Ts[c4 + 3][nr]);
      *(uint2*)&dst[(ndst + nr) * 512 + k0 + c4] = make_uint2(u0, u1);
    }
  } else {
    int idx = (bid - 1216) * 256 + t;
    int d = idx & 63;
    int rem = idx >> 6;
    int dd = rem % 1023;
    int h = rem / 1023;
    float s = fabsf(sigma[h]) + 1e-6f;
    float delta = (float)(dd - 511);
    float dt = 128.0f * tanhf(delta / s) + 128.0f;
    float lo = floorf(dt);
    int ilo = (int)lo;
    float frac = dt - lo;
    ilo = max(0, min(ilo, 256));
    int ihi = min(ilo + 1, 256);
    const float* Pb = P + h * 257 * 64;
    float val = (1.0f - frac) * Pb[ilo * 64 + d] + frac * Pb[ihi * 64 + d];
    __fp16 hv = (__fp16)val;
    Pwh[idx] = *(unsigned short*)&hv;
  }
}

// ---------------- QKV MFMA GEMM: 64x64 tile, padded LDS; v emitted TRANSPOSED ----------------
// v13: sm_scale (1/8) folded into the q store -> attn drops its per-score multiply.
__global__ __launch_bounds__(256) void qkv_mfma(
    const unsigned short* __restrict__ xb, const unsigned short* __restrict__ Wt,
    unsigned short* __restrict__ qh, unsigned short* __restrict__ kh,
    unsigned short* __restrict__ vT) {
  __shared__ unsigned short As[64][72];
  __shared__ unsigned short Bs[64][72];
  const int m0 = blockIdx.x * 64;
  const int n0 = blockIdx.y * 64;
  const int t = threadIdx.x;
  const int w = t >> 6, lane = t & 63;
  const int srow = t >> 2, sc = (t & 3) << 4;
  float4v acc[4] = {{0,0,0,0},{0,0,0,0},{0,0,0,0},{0,0,0,0}};
  for (int k0 = 0; k0 < 512; k0 += 64) {
    uint4 a0 = *(const uint4*)&xb[(m0 + srow) * 512 + k0 + sc];
    uint4 a1 = *(const uint4*)&xb[(m0 + srow) * 512 + k0 + sc + 8];
    uint4 b0 = *(const uint4*)&Wt[(n0 + srow) * 512 + k0 + sc];
    uint4 b1 = *(const uint4*)&Wt[(n0 + srow) * 512 + k0 + sc + 8];
    __syncthreads();
    *(uint4*)&As[srow][sc] = a0; *(uint4*)&As[srow][sc + 8] = a1;
    *(uint4*)&Bs[srow][sc] = b0; *(uint4*)&Bs[srow][sc + 8] = b1;
    __syncthreads();
    const int ml = (w << 4) + (lane & 15);
    const int kq = (lane >> 4) << 3;
    short8 aF0 = *(short8*)&As[ml][kq];
    short8 aF1 = *(short8*)&As[ml][kq + 32];
#pragma unroll
    for (int nt = 0; nt < 4; ++nt) {
      const int nl = (nt << 4) + (lane & 15);
      short8 bF0 = *(short8*)&Bs[nl][kq];
      short8 bF1 = *(short8*)&Bs[nl][kq + 32];
      acc[nt] = __builtin_amdgcn_mfma_f32_16x16x32_bf16(aF0, bF0, acc[nt], 0, 0, 0);
      acc[nt] = __builtin_amdgcn_mfma_f32_16x16x32_bf16(aF1, bF1, acc[nt], 0, 0, 0);
    }
  }
  const int lane15 = lane & 15;
  const int rowbase = m0 + (w << 4) + ((lane >> 4) << 2);
  if (n0 < 768) {
    // q or k head: fused RMS-norm over the 64-wide head (= this n-tile)
#pragma unroll
    for (int r = 0; r < 4; ++r) {
      float ss = 0.0f;
#pragma unroll
      for (int nt = 0; nt < 4; ++nt) ss = fmaf(acc[nt][r], acc[nt][r], ss);
#pragma unroll
      for (int off = 1; off < 16; off <<= 1) ss += __shfl_xor(ss, off, 64);
      float sc2 = 8.0f * rsqrtf(ss + 1e-6f);
      const int row = rowbase + r;
      if (n0 < 512) {
        const int h = n0 >> 6;
        const float sc3 = sc2 * 0.125f;   // fold sm_scale into q
#pragma unroll
        for (int nt = 0; nt < 4; ++nt) {
          __fp16 hv = (__fp16)(acc[nt][r] * sc3);
          qh[(row * Hh + h) * Dd + (nt << 4) + lane15] = *(unsigned short*)&hv;
        }
      } else {
        const int hkv = (n0 - 512) >> 6;
#pragma unroll
        for (int nt = 0; nt < 4; ++nt) {
          __fp16 hv = (__fp16)(acc[nt][r] * sc2);
          kh[(row * HKV + hkv) * Dd + (nt << 4) + lane15] = *(unsigned short*)&hv;
        }
      }
    }
  } else {
    // v transposed: vT[((b*HKV+hkv)*64 + d)*512 + t], 4 consecutive t per store
    const int hkv = (n0 - 768) >> 6;
    const int bb = rowbase >> 9;       // batch (64-row tile is within one b)
    const int trow = rowbase & 511;
#pragma unroll
    for (int nt = 0; nt < 4; ++nt) {
      const int d = (nt << 4) + lane15;
      unsigned u0 = h2u(__builtin_amdgcn_cvt_pkrtz(acc[nt][0], acc[nt][1]));
      unsigned u1 = h2u(__builtin_amdgcn_cvt_pkrtz(acc[nt][2], acc[nt][3]));
      *(uint2*)&vT[((bb * HKV + hkv) * 64 + d) * 512 + trow] = make_uint2(u0, u1);
    }
  }
}

// ---------------- Proj MFMA GEMM: 64x64 tile, padded LDS ----------------
__global__ __launch_bounds__(256) void proj_mfma(
    const unsigned short* __restrict__ yb, const unsigned short* __restrict__ Wt,
    float* __restrict__ out) {
  __shared__ unsigned short As[64][72];
  __shared__ unsigned short Bs[64][72];
  const int m0 = blockIdx.x * 64;
  const int n0 = blockIdx.y * 64;
  const int t = threadIdx.x;
  const int w = t >> 6, lane = t & 63;
  const int srow = t >> 2, sc = (t & 3) << 4;
  float4v acc[4] = {{0,0,0,0},{0,0,0,0},{0,0,0,0},{0,0,0,0}};
  for (int k0 = 0; k0 < 512; k0 += 64) {
    uint4 a0 = *(const uint4*)&yb[(m0 + srow) * 512 + k0 + sc];
    uint4 a1 = *(const uint4*)&yb[(m0 + srow) * 512 + k0 + sc + 8];
    uint4 b0 = *(const uint4*)&Wt[(n0 + srow) * 512 + k0 + sc];
    uint4 b1 = *(const uint4*)&Wt[(n0 + srow) * 512 + k0 + sc + 8];
    __syncthreads();
    *(uint4*)&As[srow][sc] = a0; *(uint4*)&As[srow][sc + 8] = a1;
    *(uint4*)&Bs[srow][sc] = b0; *(uint4*)&Bs[srow][sc + 8] = b1;
    __syncthreads();
    const int ml = (w << 4) + (lane & 15);
    const int kq = (lane >> 4) << 3;
    short8 aF0 = *(short8*)&As[ml][kq];
    short8 aF1 = *(short8*)&As[ml][kq + 32];
#pragma unroll
    for (int nt = 0; nt < 4; ++nt) {
      const int nl = (nt << 4) + (lane & 15);
      short8 bF0 = *(short8*)&Bs[nl][kq];
      short8 bF1 = *(short8*)&Bs[nl][kq + 32];
      acc[nt] = __builtin_amdgcn_mfma_f32_16x16x32_bf16(aF0, bF0, acc[nt], 0, 0, 0);
      acc[nt] = __builtin_amdgcn_mfma_f32_16x16x32_bf16(aF1, bF1, acc[nt], 0, 0, 0);
    }
  }
#pragma unroll
  for (int nt = 0; nt < 4; ++nt) {
    int col = n0 + (nt << 4) + (lane & 15);
#pragma unroll
    for (int r = 0; r < 4; ++r) {
      int row = m0 + (w << 4) + ((lane >> 4) << 2) + r;
      out[row * 512 + col] = acc[nt][r];
    }
  }
}

// ---------------- Attention v13: v9 structure + 4-way ILP chain split ----------------
// v9 (49.4us): VALUBusy 52% = latency-bound serial fdot2 chain (32-deep per row,
// ~4cyc latency vs 2cyc issue, only 4 waves/SIMD to cover). v12's pipeline rework
// added VALU overhead and hurt. v13 keeps v9's exact 3-barrier structure and:
//  - splits the accumulator 4 ways (per vector component): 4 independent 8-deep
//    chains -> ILP covers the fdot2 latency
//  - balanced i0 LUT (co-resident y-sets {y,y+4,y+8,y+12} all sum nt=18; was 20/16)
//  - sm_scale folded into qh (one less mul per score)
__global__ __launch_bounds__(256) void attn(
    const unsigned short* __restrict__ qh, const unsigned short* __restrict__ kh,
    const unsigned short* __restrict__ vT, const unsigned short* __restrict__ Pwh,
    unsigned short* __restrict__ yb) {
  __shared__ __fp16 PwS[96][72];
  __shared__ __fp16 pS[32][72];   // padded: A-frag start bank = 4*(i+joct) -> 2-way
  __shared__ float lS[32];

  const int t = threadIdx.x;
  const int lane = t & 63;
  const int wu = __builtin_amdgcn_readfirstlane(t >> 6);
  const int bh = blockIdx.x;
  const int b = bh >> 3;
  const int h = bh & 7;
  const int hkv = h >> 1;
  // balanced tile assignment: i0/32 = nibble y of LUT; co-res sets sum nt=18 each
  const int i0 = (int)((0x4567BA983210CDEFull >> (blockIdx.y * 4)) & 15) * 32;

  float l_lane[8];
#pragma unroll
  for (int r = 0; r < 8; ++r) l_lane[r] = 0.0f;
  float4v oacc[2] = {{0, 0, 0, 0}, {0, 0, 0, 0}};

  const int prow = (wu << 3) + 63 - lane;
  const int i_base = i0 + (wu << 3);
  const unsigned short* qbase = &qh[((b * Tt + i_base) * Hh + h) * Dd];

  // PV fragment roles
  const int i16 = (wu & 1) << 4;        // A-operand i-tile base row in pS
  const int dt0 = (wu >> 1) << 1;       // first of 2 d-tiles
  const int lm = lane & 15;
  const int kq = (lane >> 4) << 3;      // k (j) octet within 32-half
  const unsigned short* vTbase = &vT[((b * HKV + hkv) * 64) * 512];

  for (int jt0 = 0; jt0 <= i0 + 31; jt0 += 64) {
    __syncthreads();   // guards PwS restage + pS rewrite vs prior PV reads
    {
      int jr = t >> 2, dc = (t & 3) << 4;
      const int pb0 = h * 1023 + (i0 - jt0) + 448;
      const unsigned short* pwp = &Pwh[(pb0 + jr) * 64 + dc];
      *(uint4*)&PwS[jr][dc]     = *(const uint4*)&pwp[0];
      *(uint4*)&PwS[jr][dc + 8] = *(const uint4*)&pwp[8];
      int pr2 = 64 + (t >> 3), dc2 = (t & 7) << 3;
      if (pr2 < 95)
        *(uint4*)&PwS[pr2][dc2] = *(const uint4*)&Pwh[(pb0 + pr2) * 64 + dc2];
    }
    uint4 kr[8];
    {
      const uint4* kp = (const uint4*)&kh[((b * Tt + jt0 + lane) * HKV + hkv) * Dd];
#pragma unroll
      for (int c = 0; c < 8; ++c) kr[c] = kp[c];
    }
    __syncthreads();   // PwS ready

    // ---- score phase: lane = j; q broadcast from global, Pw from LDS, K regs ----
    // 4 independent accumulator chains (per component) for ILP
    const int j = jt0 + lane;
#pragma unroll
    for (int r = 0; r < 8; ++r) {
      const uint4* qp = (const uint4*)&qbase[r * (Hh * Dd)];  // wave-uniform
      float srx = 0.0f, sry = 0.0f, srz = 0.0f, srw = 0.0f;
#pragma unroll
      for (int ch = 0; ch < 8; ++ch) {
        uint4 qu = qp[ch];
        uint4 pu = *(uint4*)&PwS[prow + r][ch << 3];
        srx = fdot2(u2h(qu.x) * u2h(pu.x), u2h(kr[ch].x), srx);
        sry = fdot2(u2h(qu.y) * u2h(pu.y), u2h(kr[ch].y), sry);
        srz = fdot2(u2h(qu.z) * u2h(pu.z), u2h(kr[ch].z), srz);
        srw = fdot2(u2h(qu.w) * u2h(pu.w), u2h(kr[ch].w), srw);
      }
      float sr = (srx + sry) + (srz + srw);
      float sv = (j <= i_base + r) ? sr : -1e30f;   // sm_scale pre-folded in qh
      float p = __expf(sv - 6.0f);   // fixed shift: exact softmax, no reduce
      l_lane[r] += p;
      pS[(wu << 3) + r][lane] = (__fp16)p;   // b16 store, 2-way banks
    }
    __syncthreads();   // pS ready for all waves

    // ---- PV phase: MFMA f16, A from pS, B from vT (global, L1/L2-hot) ----
    half8 a0 = *(half8*)&pS[i16 + lm][kq];
    half8 a1 = *(half8*)&pS[i16 + lm][kq + 32];
#pragma unroll
    for (int dd = 0; dd < 2; ++dd) {
      const unsigned short* vp = vTbase + (((dt0 + dd) << 4) + lm) * 512 + jt0 + kq;
      half8 b0 = *(const half8*)&vp[0];
      half8 b1 = *(const half8*)&vp[32];
      oacc[dd] = __builtin_amdgcn_mfma_f32_16x16x32_f16(a0, b0, oacc[dd], 0, 0, 0);
      oacc[dd] = __builtin_amdgcn_mfma_f32_16x16x32_f16(a1, b1, oacc[dd], 0, 0, 0);
    }
  }

  // final l reduction (once), shared via lS (score rows != C-layout rows)
#pragma unroll
  for (int r = 0; r < 8; ++r) {
    float lr = wave_reduce_sum(l_lane[r]);
    if (lane == r) lS[(wu << 3) + r] = lr;
  }
  __syncthreads();

  // epilogue: C layout — row = i16 + quad*4 + reg, col = d-tile*16 + lm
#pragma unroll
  for (int dd = 0; dd < 2; ++dd) {
    const int d = ((dt0 + dd) << 4) + lm;
#pragma unroll
    for (int r = 0; r < 4; ++r) {
      const int irow = i16 + ((lane >> 4) << 2) + r;
      const float val = oacc[dd][r] / lS[irow];
      __hip_bfloat16 hv = __float2bfloat16(val);
      yb[((b * Tt + i0 + irow) * Hh + h) * Dd + d] = *(unsigned short*)&hv;
    }
  }
}

extern "C" void kernel_launch(void* const* d_in, const int* in_sizes, int n_in,
                              void* d_out, int out_size, void* d_ws, size_t ws_size,
                              hipStream_t stream) {
  const float* x     = (const float*)d_in[0];
  const float* Wq    = (const float*)d_in[1];
  const float* Wk    = (const float*)d_in[2];
  const float* Wv    = (const float*)d_in[3];
  const float* Wproj = (const float*)d_in[4];
  const float* P     = (const float*)d_in[5];
  const float* sigma = (const float*)d_in[6];
  float* out = (float*)d_out;

  float* ws = (float*)d_ws;
  unsigned short* qh  = (unsigned short*)ws;                // 2,097,152 h = 1,048,576 f
  unsigned short* kh  = (unsigned short*)(ws + 1048576);    // 1,048,576 h = 524,288 f
  unsigned short* vT  = (unsigned short*)(ws + 1572864);    // 1,048,576 h = 524,288 f (transposed)
  unsigned short* Pwh = (unsigned short*)(ws + 2097152);    // 523,776 h -> 262,144 f
  unsigned short* xb  = (unsigned short*)(ws + 2359296);    // 2M bf16 = 1,048,576 f
  unsigned short* yb  = xb;                                 // alias: xb dead after qkv_mfma
  unsigned short* Wtq = (unsigned short*)(ws + 3407872);    // 524,288 h = 262,144 f
  unsigned short* Wtp = (unsigned short*)(ws + 3670016);    // 262,144 h = 131,072 f

  prep<<<dim3(3262), 256, 0, stream>>>(x, Wq, Wk, Wv, Wproj, P, sigma,
                                       xb, Wtq, Wtp, Pwh);
  qkv_mfma<<<dim3(64, 16), 256, 0, stream>>>(xb, Wtq, qh, kh, vT);
  attn<<<dim3(64, 16), 256, 0, stream>>>(qh, kh, vT, Pwh, yb);
  proj_mfma<<<dim3(64, 8), 256, 0, stream>>>(yb, Wtp, out);
}